// Round 4
// baseline (478.105 us; speedup 1.0000x reference)
//
#include <hip/hip_runtime.h>
#include <math.h>

#define NB   8
#define NW   200
#define NK   100
#define KSZ  7
#define NHID 150
#define NFE  400
#define NTE  200
#define NG   450   // 3*HID
#define NCIN 300   // 3*K
#define ALPHAC 0.2f

typedef __attribute__((ext_vector_type(8))) short bf8;
typedef __attribute__((ext_vector_type(4))) float f32x4;

__device__ __forceinline__ float sigmoidf_(float x){
  return 1.0f/(1.0f + __expf(-x));
}
__device__ __forceinline__ float tanhf_(float x){
  float xc = fminf(fmaxf(x, -15.f), 15.f);
  float e = __expf(2.f*xc);
  return (e - 1.f)/(e + 1.f);
}
__device__ __forceinline__ unsigned short f2bf(float f){
  unsigned int u = __float_as_uint(f);
  unsigned int r = u + 0x7FFFu + ((u>>16)&1u);
  return (unsigned short)(r>>16);
}

// ---------------- weight prep: conv transpose, w_ih transpose, w_hh -> MFMA B-fragments ----------------
// Bfrag layout: 32 N-tiles x 5 K-steps x 64 lanes x 4 dwords (8 bf16).
// Lane l, elem e (0..7): k = ks*32 + (l>>4)*8 + e, col = tile*16 + (l&15).
// B[k][c] = w_hh[c*150 + k] (zero-padded k>=150, c>=450).
__global__ void prep_kernel(const float* conv_w, const float* w_ih, const float* w_hh,
                            float* conv_wT, float* w_ihT, unsigned int* Bfrag){
  int idx = blockIdx.x*256 + threadIdx.x;
  const int n1 = NK*NK*KSZ;      // 70000
  const int n2 = NG*NCIN;        // 135000
  const int n3 = 32*5*64*4;      // 40960 dwords
  if (idx < n1){
    int k = idx % NK; int it = idx / NK;       // it = i*KSZ + t
    int i = it / KSZ, t = it % KSZ;
    conv_wT[idx] = conv_w[(k*NK + i)*KSZ + t];
  } else if (idx < n1 + n2){
    int o = idx - n1; int g = o % NG; int c = o / NG;
    w_ihT[o] = w_ih[g*NCIN + c];
  } else if (idx < n1 + n2 + n3){
    int o = idx - n1 - n2;
    int n   = o / 1280;
    int rem = o % 1280;
    int ks  = rem / 256;
    int rem2= rem % 256;
    int l   = rem2 >> 2;
    int d   = rem2 & 3;
    int col = n*16 + (l & 15);
    int k0  = ks*32 + (l >> 4)*8 + d*2;
    unsigned short lo = 0, hi = 0;
    if (col < NG){
      if (k0     < NHID) lo = f2bf(w_hh[col*NHID + k0]);
      if (k0 + 1 < NHID) hi = f2bf(w_hh[col*NHID + k0 + 1]);
    }
    Bfrag[o] = ((unsigned int)hi << 16) | lo;
  }
}

// ---------------- conv1d + bias + relu -> xc (B,W,K) ----------------
__global__ void conv_kernel(const float* x, const float* conv_b, const float* conv_wT, float* xc){
  int idx = blockIdx.x*256 + threadIdx.x;
  if (idx >= NB*NW*NK) return;
  int k = idx % NK; int w = (idx/NK) % NW; int b = idx/(NK*NW);
  float acc = conv_b[k];
  const float* xb = x + b*NW*NK;
  for (int t = 0; t < KSZ; ++t){
    int ws = w + t - 3;
    if (ws < 0 || ws >= NW) continue;
    const float* xr = xb + ws*NK;
    const float* wr = conv_wT + t*NK + k;   // (i*KSZ+t)*NK + k
    #pragma unroll 4
    for (int i = 0; i < NK; ++i){
      acc += xr[i] * wr[i*KSZ*NK];
    }
  }
  xc[idx] = fmaxf(acc, 0.0f);
}

// ---------------- f-GAT si/sj: (B,K,FE), nodes=features, v[b,n,d]=xc[b,d,n] ----------------
__global__ void fgat_sisj(const float* xc, const float* f_lin_w, float* si, float* sj){
  __shared__ __align__(16) float vt[NW*4];
  int b = blockIdx.x / 25; int n0 = (blockIdx.x % 25)*4;
  int tid = threadIdx.x;
  for (int idx = tid; idx < NW*4; idx += 512){
    int d = idx >> 2, nn = idx & 3;
    vt[idx] = xc[(b*NW + d)*NK + n0 + nn];
  }
  __syncthreads();
  if (tid >= NFE) return;
  int e = tid;
  float a1[4] = {0,0,0,0}, a2[4] = {0,0,0,0};
  for (int d = 0; d < NW; ++d){
    float w1 = f_lin_w[d*NFE + e];
    float w2 = f_lin_w[(NW + d)*NFE + e];
    float4 v = *(const float4*)&vt[d*4];
    a1[0] += v.x*w1; a1[1] += v.y*w1; a1[2] += v.z*w1; a1[3] += v.w*w1;
    a2[0] += v.x*w2; a2[1] += v.y*w2; a2[2] += v.z*w2; a2[3] += v.w*w2;
  }
  #pragma unroll
  for (int nn = 0; nn < 4; ++nn){
    si[(b*NK + n0+nn)*NFE + e] = a1[nn];
    sj[(b*NK + n0+nn)*NFE + e] = a2[nn];
  }
}

// ---------------- t-GAT si/sj: (B,W,TE), nodes=time, v[b,n,d]=xc[b,n,d] ----------------
__global__ void tgat_sisj(const float* xc, const float* t_lin_w, float* si, float* sj){
  __shared__ __align__(16) float vt[NK*4];
  int b = blockIdx.x / 50; int n0 = (blockIdx.x % 50)*4;
  int tid = threadIdx.x;
  for (int idx = tid; idx < NK*4; idx += 256){
    int d = idx >> 2, nn = idx & 3;
    vt[idx] = xc[(b*NW + n0+nn)*NK + d];
  }
  __syncthreads();
  if (tid >= NTE) return;
  int e = tid;
  float a1[4] = {0,0,0,0}, a2[4] = {0,0,0,0};
  for (int d = 0; d < NK; ++d){
    float w1 = t_lin_w[d*NTE + e];
    float w2 = t_lin_w[(NK + d)*NTE + e];
    float4 v = *(const float4*)&vt[d*4];
    a1[0] += v.x*w1; a1[1] += v.y*w1; a1[2] += v.z*w1; a1[3] += v.w*w1;
    a2[0] += v.x*w2; a2[1] += v.y*w2; a2[2] += v.z*w2; a2[3] += v.w*w2;
  }
  #pragma unroll
  for (int nn = 0; nn < 4; ++nn){
    si[(b*NW + n0+nn)*NTE + e] = a1[nn];
    sj[(b*NW + n0+nn)*NTE + e] = a2[nn];
  }
}

// ---------------- f-GAT attention fused: e -> softmax -> sigmoid(attn@v) ----------------
// out written transposed into (B,W,K): h_featT[b,d,i]
__global__ void fgat_attn(const float* xc, const float* si, const float* sj,
                          const float* f_lin_b, const float* f_a, const float* f_bias,
                          float* h_featT){
  __shared__ float sib[NFE], av[NFE], attn[NK], red[128];
  int b = blockIdx.x / NK, i = blockIdx.x % NK;
  int tid = threadIdx.x;
  for (int e = tid; e < NFE; e += 128){
    sib[e] = si[(b*NK + i)*NFE + e] + f_lin_b[e];
    av[e]  = f_a[e];
  }
  __syncthreads();
  float ej = -1e30f;
  if (tid < NK){
    const float* sjr = sj + (b*NK + tid)*NFE;
    float acc = 0.f;
    for (int e = 0; e < NFE; ++e){
      float tv = sib[e] + sjr[e];
      float lk = fmaxf(tv, 0.f) + ALPHAC*fminf(tv, 0.f);
      acc += av[e]*lk;
    }
    ej = acc + f_bias[i*NK + tid];
  }
  red[tid] = ej; __syncthreads();
  for (int s = 64; s > 0; s >>= 1){ if (tid < s) red[tid] = fmaxf(red[tid], red[tid+s]); __syncthreads(); }
  float m = red[0]; __syncthreads();
  float ex = (tid < NK) ? __expf(ej - m) : 0.f;
  red[tid] = ex; __syncthreads();
  for (int s = 64; s > 0; s >>= 1){ if (tid < s) red[tid] += red[tid+s]; __syncthreads(); }
  float denom = red[0];
  if (tid < NK) attn[tid] = ex / denom;
  __syncthreads();
  for (int d = tid; d < NW; d += 128){
    const float* xr = xc + (b*NW + d)*NK;    // v[b,j,d] = xc[b,d,j]
    float acc = 0.f;
    for (int j = 0; j < NK; ++j) acc += attn[j]*xr[j];
    h_featT[(b*NW + d)*NK + i] = sigmoidf_(acc);
  }
}

// ---------------- t-GAT attention fused -> h_temp (B,W,K) ----------------
__global__ void tgat_attn(const float* xc, const float* si, const float* sj,
                          const float* t_lin_b, const float* t_a, const float* t_bias,
                          float* h_temp){
  __shared__ float sib[NTE], av[NTE], attn[NW], red[256];
  int b = blockIdx.x / NW, i = blockIdx.x % NW;
  int tid = threadIdx.x;
  for (int e = tid; e < NTE; e += 256){
    sib[e] = si[(b*NW + i)*NTE + e] + t_lin_b[e];
    av[e]  = t_a[e];
  }
  __syncthreads();
  float ej = -1e30f;
  if (tid < NW){
    const float* sjr = sj + (b*NW + tid)*NTE;
    float acc = 0.f;
    for (int e = 0; e < NTE; ++e){
      float tv = sib[e] + sjr[e];
      float lk = fmaxf(tv, 0.f) + ALPHAC*fminf(tv, 0.f);
      acc += av[e]*lk;
    }
    ej = acc + t_bias[i*NW + tid];
  }
  red[tid] = ej; __syncthreads();
  for (int s = 128; s > 0; s >>= 1){ if (tid < s) red[tid] = fmaxf(red[tid], red[tid+s]); __syncthreads(); }
  float m = red[0]; __syncthreads();
  float ex = (tid < NW) ? __expf(ej - m) : 0.f;
  red[tid] = ex; __syncthreads();
  for (int s = 128; s > 0; s >>= 1){ if (tid < s) red[tid] += red[tid+s]; __syncthreads(); }
  float denom = red[0];
  if (tid < NW) attn[tid] = ex / denom;
  __syncthreads();
  for (int d = tid; d < NK; d += 256){
    float acc = 0.f;
    for (int j = 0; j < NW; ++j) acc += attn[j]*xc[(b*NW + j)*NK + d];
    h_temp[(b*NW + i)*NK + d] = sigmoidf_(acc);
  }
}

// ---------------- gi = h_cat @ w_ih^T + b_ih, layout (t, b, g) ----------------
__global__ void gi_kernel(const float* xc, const float* h_featT, const float* h_temp,
                          const float* w_ihT, const float* b_ih, float* gi){
  __shared__ __align__(16) float hc[NCIN*8];   // [c][tt], stride 8
  int b = blockIdx.x / 25; int t0 = (blockIdx.x % 25)*8;
  int tid = threadIdx.x;
  for (int idx = tid; idx < NCIN*8; idx += 512){
    int tt = idx / NCIN; int c = idx % NCIN;
    int base = (b*NW + t0 + tt)*NK;
    float v;
    if (c < NK)        v = xc[base + c];
    else if (c < 2*NK) v = h_featT[base + c - NK];
    else               v = h_temp[base + c - 2*NK];
    hc[c*8 + tt] = v;
  }
  __syncthreads();
  if (tid >= NG) return;
  int g = tid;
  float bi = b_ih[g];
  float acc[8];
  #pragma unroll
  for (int tt = 0; tt < 8; ++tt) acc[tt] = bi;
  for (int c = 0; c < NCIN; ++c){
    float wv = w_ihT[c*NG + g];
    float4 h0 = *(const float4*)&hc[c*8];
    float4 h1 = *(const float4*)&hc[c*8+4];
    acc[0] += h0.x*wv; acc[1] += h0.y*wv; acc[2] += h0.z*wv; acc[3] += h0.w*wv;
    acc[4] += h1.x*wv; acc[5] += h1.y*wv; acc[6] += h1.z*wv; acc[7] += h1.w*wv;
  }
  #pragma unroll
  for (int tt = 0; tt < 8; ++tt)
    gi[((t0+tt)*NB + b)*NG + g] = acc[tt];
}

// ---------------- sequential GRU: one block, all 8 batches, MFMA ----------------
// Per step: gh[16x512] = (h_hi + h_lo)[16x160]bf16 @ W[160x512]bf16 via
// mfma_f32_16x16x32_bf16. 8 waves x 4 N-tiles. B-fragments in 20 NAMED
// registers/lane (rounds 1-3: any per-thread ARRAY got allocaed to scratch).
// A/B share one k-permutation (cancels by dot-product invariance); C layout
// is the HW-verified col=lane&15, row=(lane>>4)*4+reg.
#define MM(C, A, Bf) C = __builtin_amdgcn_mfma_f32_16x16x32_bf16(A, Bf, C, 0, 0, 0);
#define TILE_MM(C, K0,K1,K2,K3,K4) \
  MM(C,aH0,K0) MM(C,aL0,K0) MM(C,aH1,K1) MM(C,aL1,K1) MM(C,aH2,K2) MM(C,aL2,K2) \
  MM(C,aH3,K3) MM(C,aL3,K3) MM(C,aH4,K4) MM(C,aL4,K4)
#define LDB(NM, TL, KS) bf8 NM = Bfrag[((TL)*5 + (KS))*64 + lane];

__global__ void __launch_bounds__(512, 2) gru_kernel(const float* gi, const bf8* Bfrag,
                                                     const float* b_hh, float* out){
  __shared__ __align__(16) unsigned short h_hi[16*176];
  __shared__ __align__(16) unsigned short h_lo[16*176];
  __shared__ __align__(16) float h_f32[8*152];
  __shared__ __align__(16) float gh[16*516];
  int tid = threadIdx.x;
  int lane = tid & 63;
  int wv = tid >> 6;            // wave 0..7
  int agrp = lane >> 4;         // 0..3
  int arow = lane & 15;
  int crow = agrp*4;
  int ccol = arow;

  // gate-phase pair assignments (fixed per thread)
  int p0 = tid, p1 = tid + 512, p2 = tid + 1024;
  int b0 = p0/NHID, u0 = p0%NHID;
  int b1 = p1/NHID, u1 = p1%NHID;
  bool v2 = (p2 < NB*NHID);
  int b2 = v2 ? p2/NHID : 0, u2 = v2 ? p2%NHID : 0;
  float bhr0 = b_hh[u0],      bhz0 = b_hh[NHID+u0],  bhn0 = b_hh[2*NHID+u0];
  float bhr1 = b_hh[u1],      bhz1 = b_hh[NHID+u1],  bhn1 = b_hh[2*NHID+u1];
  float bhr2 = b_hh[u2],      bhz2 = b_hh[NHID+u2],  bhn2 = b_hh[2*NHID+u2];

  // B-fragments: tiles wv, wv+8, wv+16, wv+24 (named, loop-invariant)
  LDB(W00,wv,0)    LDB(W01,wv,1)    LDB(W02,wv,2)    LDB(W03,wv,3)    LDB(W04,wv,4)
  LDB(W10,wv+8,0)  LDB(W11,wv+8,1)  LDB(W12,wv+8,2)  LDB(W13,wv+8,3)  LDB(W14,wv+8,4)
  LDB(W20,wv+16,0) LDB(W21,wv+16,1) LDB(W22,wv+16,2) LDB(W23,wv+16,3) LDB(W24,wv+16,4)
  LDB(W30,wv+24,0) LDB(W31,wv+24,1) LDB(W32,wv+24,2) LDB(W33,wv+24,3) LDB(W34,wv+24,4)

  for (int i = tid; i < 16*176; i += 512){ h_hi[i] = 0; h_lo[i] = 0; }
  for (int i = tid; i < 8*152;  i += 512){ h_f32[i] = 0.f; }
  __syncthreads();

  const bf8* HH = (const bf8*)h_hi;
  const bf8* HL = (const bf8*)h_lo;
  int abase = arow*22 + agrp;   // bf8 units; row stride 176 bf16 = 22 bf8

  for (int t = 0; t < NW; ++t){
    // prefetch this step's gi (consumed after barrier 1)
    const float* gt = gi + t*NB*NG;
    float gr0 = gt[b0*NG+u0], gz0 = gt[b0*NG+NHID+u0], gn0 = gt[b0*NG+2*NHID+u0];
    float gr1 = gt[b1*NG+u1], gz1 = gt[b1*NG+NHID+u1], gn1 = gt[b1*NG+2*NHID+u1];
    float gr2 = 0.f, gz2 = 0.f, gn2 = 0.f;
    if (v2){ gr2 = gt[b2*NG+u2]; gz2 = gt[b2*NG+NHID+u2]; gn2 = gt[b2*NG+2*NHID+u2]; }

    // A fragments (hi/lo), shared across this wave's 4 tiles
    bf8 aH0 = HH[abase],    aH1 = HH[abase+4],  aH2 = HH[abase+8],
        aH3 = HH[abase+12], aH4 = HH[abase+16];
    bf8 aL0 = HL[abase],    aL1 = HL[abase+4],  aL2 = HL[abase+8],
        aL3 = HL[abase+12], aL4 = HL[abase+16];

    f32x4 c0 = {0.f,0.f,0.f,0.f}, c1 = {0.f,0.f,0.f,0.f},
          c2 = {0.f,0.f,0.f,0.f}, c3 = {0.f,0.f,0.f,0.f};
    TILE_MM(c0, W00,W01,W02,W03,W04)
    TILE_MM(c1, W10,W11,W12,W13,W14)
    TILE_MM(c2, W20,W21,W22,W23,W24)
    TILE_MM(c3, W30,W31,W32,W33,W34)

    if (agrp < 2){   // rows 0..7 are real batches
      float* g0 = &gh[crow*516 + (wv   )*16 + ccol];
      float* g1 = &gh[crow*516 + (wv+ 8)*16 + ccol];
      float* g2 = &gh[crow*516 + (wv+16)*16 + ccol];
      float* g3 = &gh[crow*516 + (wv+24)*16 + ccol];
      g0[0]=c0[0]; g0[516]=c0[1]; g0[1032]=c0[2]; g0[1548]=c0[3];
      g1[0]=c1[0]; g1[516]=c1[1]; g1[1032]=c1[2]; g1[1548]=c1[3];
      g2[0]=c2[0]; g2[516]=c2[1]; g2[1032]=c2[2]; g2[1548]=c2[3];
      g3[0]=c3[0]; g3[516]=c3[1]; g3[1032]=c3[2]; g3[1548]=c3[3];
    }
    __syncthreads();

    // gate phase
    {
      float r = sigmoidf_(gr0 + gh[b0*516+u0] + bhr0);
      float z = sigmoidf_(gz0 + gh[b0*516+NHID+u0] + bhz0);
      float n = tanhf_  (gn0 + r*(gh[b0*516+2*NHID+u0] + bhn0));
      float hold = h_f32[b0*152+u0];
      float hn = (1.f - z)*n + z*hold;
      h_f32[b0*152+u0] = hn;
      unsigned int ub = __float_as_uint(hn);
      unsigned int hi = (ub + 0x7FFFu + ((ub>>16)&1u)) >> 16;
      h_hi[b0*176+u0] = (unsigned short)hi;
      float lo = hn - __uint_as_float(hi<<16);
      unsigned int ul = __float_as_uint(lo);
      h_lo[b0*176+u0] = (unsigned short)((ul + 0x7FFFu + ((ul>>16)&1u)) >> 16);
    }
    {
      float r = sigmoidf_(gr1 + gh[b1*516+u1] + bhr1);
      float z = sigmoidf_(gz1 + gh[b1*516+NHID+u1] + bhz1);
      float n = tanhf_  (gn1 + r*(gh[b1*516+2*NHID+u1] + bhn1));
      float hold = h_f32[b1*152+u1];
      float hn = (1.f - z)*n + z*hold;
      h_f32[b1*152+u1] = hn;
      unsigned int ub = __float_as_uint(hn);
      unsigned int hi = (ub + 0x7FFFu + ((ub>>16)&1u)) >> 16;
      h_hi[b1*176+u1] = (unsigned short)hi;
      float lo = hn - __uint_as_float(hi<<16);
      unsigned int ul = __float_as_uint(lo);
      h_lo[b1*176+u1] = (unsigned short)((ul + 0x7FFFu + ((ul>>16)&1u)) >> 16);
    }
    if (v2){
      float r = sigmoidf_(gr2 + gh[b2*516+u2] + bhr2);
      float z = sigmoidf_(gz2 + gh[b2*516+NHID+u2] + bhz2);
      float n = tanhf_  (gn2 + r*(gh[b2*516+2*NHID+u2] + bhn2));
      float hold = h_f32[b2*152+u2];
      float hn = (1.f - z)*n + z*hold;
      h_f32[b2*152+u2] = hn;
      unsigned int ub = __float_as_uint(hn);
      unsigned int hi = (ub + 0x7FFFu + ((ub>>16)&1u)) >> 16;
      h_hi[b2*176+u2] = (unsigned short)hi;
      float lo = hn - __uint_as_float(hi<<16);
      unsigned int ul = __float_as_uint(lo);
      h_lo[b2*176+u2] = (unsigned short)((ul + 0x7FFFu + ((ul>>16)&1u)) >> 16);
    }
    __syncthreads();
  }

  out[b0*NHID + u0] = h_f32[b0*152 + u0];
  out[b1*NHID + u1] = h_f32[b1*152 + u1];
  if (v2) out[b2*NHID + u2] = h_f32[b2*152 + u2];
}

extern "C" void kernel_launch(void* const* d_in, const int* in_sizes, int n_in,
                              void* d_out, int out_size, void* d_ws, size_t ws_size,
                              hipStream_t stream){
  const float* x       = (const float*)d_in[0];
  const float* conv_w  = (const float*)d_in[1];
  const float* conv_b  = (const float*)d_in[2];
  const float* f_lin_w = (const float*)d_in[3];
  const float* f_lin_b = (const float*)d_in[4];
  const float* f_a     = (const float*)d_in[5];
  const float* f_bias  = (const float*)d_in[6];
  const float* t_lin_w = (const float*)d_in[7];
  const float* t_lin_b = (const float*)d_in[8];
  const float* t_a     = (const float*)d_in[9];
  const float* t_bias  = (const float*)d_in[10];
  const float* w_ih    = (const float*)d_in[11];
  const float* w_hh    = (const float*)d_in[12];
  const float* b_ih    = (const float*)d_in[13];
  const float* b_hh    = (const float*)d_in[14];

  float* ws      = (float*)d_ws;
  float* xc      = ws;               // 160000
  float* conv_wT = ws + 160000;      // 70000
  float* si_f    = ws + 230000;      // 320000
  float* sj_f    = ws + 550000;      // 320000
  float* h_featT = ws + 870000;      // 160000
  float* si_t    = ws + 1030000;     // 320000
  float* sj_t    = ws + 1350000;     // 320000
  float* h_temp  = ws + 1670000;     // 160000
  float* w_ihT   = ws + 1830000;     // 135000
  float* gi      = ws + 1965000;     // 720000
  float* BfragF  = ws + 2685000;     // 40960 dwords (16B-aligned offset)
                                     // total 2725960 floats ~= 10.9 MB

  prep_kernel<<<961, 256, 0, stream>>>(conv_w, w_ih, w_hh, conv_wT, w_ihT, (unsigned int*)BfragF);
  conv_kernel<<<(NB*NW*NK + 255)/256, 256, 0, stream>>>(x, conv_b, conv_wT, xc);
  fgat_sisj<<<NB*25, 512, 0, stream>>>(xc, f_lin_w, si_f, sj_f);
  tgat_sisj<<<NB*50, 256, 0, stream>>>(xc, t_lin_w, si_t, sj_t);
  fgat_attn<<<NB*NK, 128, 0, stream>>>(xc, si_f, sj_f, f_lin_b, f_a, f_bias, h_featT);
  tgat_attn<<<NB*NW, 256, 0, stream>>>(xc, si_t, sj_t, t_lin_b, t_a, t_bias, h_temp);
  gi_kernel<<<NB*25, 512, 0, stream>>>(xc, h_featT, h_temp, w_ihT, b_ih, gi);
  gru_kernel<<<1, 512, 0, stream>>>(gi, (const bf8*)BfragF, b_hh, (float*)d_out);
}